// Round 1
// baseline (395.567 us; speedup 1.0000x reference)
//
#include <hip/hip_runtime.h>
#include <hip/hip_bf16.h>
#include <stdint.h>

#define NROWS 65536
#define IN_D  512
#define NE    4096
#define ED    64

typedef __attribute__((ext_vector_type(8)))  __bf16 bf16x8;
typedef __attribute__((ext_vector_type(4)))  float  f32x4;
typedef __attribute__((ext_vector_type(16))) float  f32x16;

static __device__ __forceinline__ __bf16 tobf(float f) { return (__bf16)f; }

// ---------------------------------------------------------------------------
// K0: prep. Block ranges do independent jobs:
//  [0,256)    : D[4096][512] = emb @ W_out + b_out   (16 codes / block)
//  [256,1280) : Efrag  — emb cast to bf16, packed in 32x32x16 B-fragment order
//  [1280,1408): Wfrag  — W_in cast to bf16, packed in 16x16x32 B-fragment order
//  [1408,1424): chalf[c] = 0.5*||emb_c||^2
//  [1424,1440): zero counts ; 1440: zero sse
// ---------------------------------------------------------------------------
__global__ __launch_bounds__(256) void k_prep(
    const float* __restrict__ emb, const float* __restrict__ W_in,
    const float* __restrict__ W_out, const float* __restrict__ b_out,
    float* __restrict__ D, __bf16* __restrict__ Efrag, __bf16* __restrict__ Wfrag,
    float* __restrict__ chalf, unsigned* __restrict__ counts, float* __restrict__ sse)
{
  __shared__ __align__(16) float elds[16 * 64];
  int bid = blockIdx.x, tid = threadIdx.x;

  if (bid < 256) {                       // ---- D table ----
    int c0 = bid * 16;
    for (int i = tid; i < 16 * 64; i += 256) elds[i] = emb[c0 * 64 + i];
    __syncthreads();
    float a0[16], a1[16];
#pragma unroll
    for (int c = 0; c < 16; ++c) { a0[c] = 0.f; a1[c] = 0.f; }
    int j = tid;
    for (int d4 = 0; d4 < 64; d4 += 4) {
      float w0[4], w1[4];
#pragma unroll
      for (int dd = 0; dd < 4; ++dd) {
        w0[dd] = W_out[(d4 + dd) * 512 + j];
        w1[dd] = W_out[(d4 + dd) * 512 + 256 + j];
      }
#pragma unroll
      for (int c = 0; c < 16; ++c) {
        f32x4 ev = *(const f32x4*)&elds[c * 64 + d4];
        a0[c] += ev[0] * w0[0] + ev[1] * w0[1] + ev[2] * w0[2] + ev[3] * w0[3];
        a1[c] += ev[0] * w1[0] + ev[1] * w1[1] + ev[2] * w1[2] + ev[3] * w1[3];
      }
    }
    float bo0 = b_out[j], bo1 = b_out[256 + j];
#pragma unroll
    for (int c = 0; c < 16; ++c) {
      D[(size_t)(c0 + c) * 512 + j]       = a0[c] + bo0;
      D[(size_t)(c0 + c) * 512 + 256 + j] = a1[c] + bo1;
    }
  } else if (bid < 1280) {               // ---- Efrag ----
    int e = (bid - 256) * 256 + tid;     // 0..262143
    int i = e & 7, lane = (e >> 3) & 63, s = (e >> 9) & 3, ct = e >> 11;
    int code = ct * 32 + (lane & 31);
    int k    = s * 16 + ((lane >> 5) << 3) + i;
    Efrag[e] = tobf(emb[code * 64 + k]);
  } else if (bid < 1408) {               // ---- Wfrag ----
    int e = (bid - 1280) * 256 + tid;    // 0..32767
    int i = e & 7, lane = (e >> 3) & 63, t = (e >> 9) & 3, s = e >> 11;
    int k = s * 32 + ((lane >> 4) << 3) + i;
    int n = t * 16 + (lane & 15);
    Wfrag[e] = tobf(W_in[k * 64 + n]);
  } else if (bid < 1424) {               // ---- chalf ----
    int c = (bid - 1408) * 256 + tid;
    const f32x4* er = (const f32x4*)(emb + c * 64);
    float s = 0.f;
#pragma unroll
    for (int i2 = 0; i2 < 16; ++i2) {
      f32x4 v = er[i2];
      s += v[0] * v[0] + v[1] * v[1] + v[2] * v[2] + v[3] * v[3];
    }
    chalf[c] = 0.5f * s;
  } else if (bid < 1440) {               // ---- zero counts ----
    counts[(bid - 1424) * 256 + tid] = 0u;
  } else {
    if (tid == 0) sse[0] = 0.f;
  }
}

// ---------------------------------------------------------------------------
// K1: X[n][64] = bf16( inputs @ W_in + b_in ).  MFMA 16x16x32, BM=128/block,
// each wave does 32 rows (two 16-row groups sharing B-fragments).
// ---------------------------------------------------------------------------
__global__ __launch_bounds__(256) void k_xproj(
    const float* __restrict__ in, const bf16x8* __restrict__ Wfv,
    const float* __restrict__ b_in, __bf16* __restrict__ X)
{
  int tid = threadIdx.x, lane = tid & 63, wv = tid >> 6;
  int rbase = blockIdx.x * 128 + wv * 32;
  const float* p0 = in + (size_t)(rbase + (lane & 15)) * 512 + ((lane >> 4) << 3);
  const float* p1 = p0 + 16 * 512;

  f32x4 acc[2][4];
#pragma unroll
  for (int g = 0; g < 2; ++g)
#pragma unroll
    for (int t = 0; t < 4; ++t) acc[g][t] = (f32x4){0.f, 0.f, 0.f, 0.f};

  for (int s = 0; s < 16; ++s) {
    f32x4 u0 = *(const f32x4*)(p0 + s * 32);
    f32x4 u1 = *(const f32x4*)(p0 + s * 32 + 4);
    f32x4 v0 = *(const f32x4*)(p1 + s * 32);
    f32x4 v1 = *(const f32x4*)(p1 + s * 32 + 4);
    bf16x8 A0, A1;
#pragma unroll
    for (int i = 0; i < 4; ++i) {
      A0[i] = tobf(u0[i]); A0[4 + i] = tobf(u1[i]);
      A1[i] = tobf(v0[i]); A1[4 + i] = tobf(v1[i]);
    }
#pragma unroll
    for (int t = 0; t < 4; ++t) {
      bf16x8 B = Wfv[(s * 4 + t) * 64 + lane];
      acc[0][t] = __builtin_amdgcn_mfma_f32_16x16x32_bf16(A0, B, acc[0][t], 0, 0, 0);
      acc[1][t] = __builtin_amdgcn_mfma_f32_16x16x32_bf16(A1, B, acc[1][t], 0, 0, 0);
    }
  }
  int crow = rbase + ((lane >> 4) << 2);
#pragma unroll
  for (int t = 0; t < 4; ++t) {
    int col = t * 16 + (lane & 15);
    float bi = b_in[col];
#pragma unroll
    for (int r = 0; r < 4; ++r) {
      X[(size_t)(crow + r) * 64 + col]      = tobf(acc[0][t][r] + bi);
      X[(size_t)(crow + 16 + r) * 64 + col] = tobf(acc[1][t][r] + bi);
    }
  }
}

// ---------------------------------------------------------------------------
// K2: argmin over codes via MFMA 32x32x16, index packed into score mantissa.
// BM=128/block (32 rows/wave), codebook tiles double-buffered in LDS.
// Fused histogram (LDS, then global atomics).
// ---------------------------------------------------------------------------
__global__ __launch_bounds__(256) void k_argmin(
    const __bf16* __restrict__ X, const bf16x8* __restrict__ Efv,
    const float* __restrict__ chalf, unsigned* __restrict__ idxout,
    unsigned* __restrict__ counts)
{
  __shared__ unsigned hist[NE];
  __shared__ bf16x8 Ebuf[2][256];
  int tid = threadIdx.x;
  for (int i = tid; i < NE; i += 256) hist[i] = 0u;

  int lane = tid & 63, wv = tid >> 6;
  int rbase = blockIdx.x * 128 + wv * 32;
  int row = rbase + (lane & 31);
  const bf16x8* Xv = (const bf16x8*)X;
  bf16x8 A[4];
#pragma unroll
  for (int s = 0; s < 4; ++s) A[s] = Xv[row * 8 + s * 2 + (lane >> 5)];

  float best[16];
#pragma unroll
  for (int r = 0; r < 16; ++r) best[r] = -3.0e38f;
  int cl = lane & 31;

  Ebuf[0][tid] = Efv[tid];            // stage tile 0
  __syncthreads();

  for (int ct = 0; ct < 128; ++ct) {
    int cur = ct & 1;
    if (ct + 1 < 128) Ebuf[cur ^ 1][tid] = Efv[(ct + 1) * 256 + tid];
    float ch = chalf[ct * 32 + cl];
    f32x16 acc = {};
#pragma unroll
    for (int s = 0; s < 4; ++s)
      acc = __builtin_amdgcn_mfma_f32_32x32x16_bf16(A[s], Ebuf[cur][s * 64 + lane], acc, 0, 0, 0);
    unsigned code = (unsigned)(ct * 32 + cl);
#pragma unroll
    for (int r = 0; r < 16; ++r) {
      float adj = acc[r] - ch;
      unsigned u = (__float_as_uint(adj) & 0xFFFFF000u) | (code & 0xFFFu);  // v_bfi
      best[r] = fmaxf(best[r], __uint_as_float(u));
    }
    __syncthreads();
  }
#pragma unroll
  for (int m = 1; m < 32; m <<= 1) {
#pragma unroll
    for (int r = 0; r < 16; ++r) best[r] = fmaxf(best[r], __shfl_xor(best[r], m, 64));
  }
  int r = lane & 31;
  if (r < 16) {
    int rowabs = rbase + (r & 3) + ((r >> 2) << 3) + ((lane >> 5) << 2);
    unsigned code = __float_as_uint(best[r]) & 0xFFFu;
    idxout[rowabs] = code;
    atomicAdd(&hist[code], 1u);
  }
  __syncthreads();
  for (int i = tid; i < NE; i += 256) {
    unsigned v = hist[i];
    if (v) atomicAdd(&counts[i], v);
  }
}

// ---------------------------------------------------------------------------
// K3: out[n] = D[idx[n]] (== quantized forward value), fused SSE(q, inputs).
// 32 rows/block; each iteration = exactly one row across 256 threads (float2).
// ---------------------------------------------------------------------------
__global__ __launch_bounds__(256) void k_output(
    const float* __restrict__ in, const float* __restrict__ Dtab,
    const unsigned* __restrict__ idx, float* __restrict__ out, float* __restrict__ sse)
{
  __shared__ float ws4[4];
  int tid = threadIdx.x, base = blockIdx.x * 32;
  float lsum = 0.f;
  for (int rr = 0; rr < 32; ++rr) {
    int n = base + rr;
    unsigned c = idx[n];
    float2 x = ((const float2*)(in  + (size_t)n * 512))[tid];
    float2 q = ((const float2*)(Dtab + (size_t)c * 512))[tid];
    ((float2*)(out + (size_t)n * 512))[tid] = q;
    float dx = q.x - x.x, dy = q.y - x.y;
    lsum += dx * dx + dy * dy;
  }
  for (int off = 32; off; off >>= 1) lsum += __shfl_down(lsum, off, 64);
  if ((tid & 63) == 0) ws4[tid >> 6] = lsum;
  __syncthreads();
  if (tid == 0) atomicAdd(sse, ws4[0] + ws4[1] + ws4[2] + ws4[3]);
}

// ---------------------------------------------------------------------------
// K4: loss + perplexity scalars.
// ---------------------------------------------------------------------------
__global__ __launch_bounds__(256) void k_final(
    const unsigned* __restrict__ counts, const float* __restrict__ sse,
    float* __restrict__ out)
{
  __shared__ float ws4[4];
  int tid = threadIdx.x;
  float local = 0.f;
  for (int i = tid; i < NE; i += 256) {
    float p = (float)counts[i] * (1.0f / 65536.0f);
    local += p * logf(p + 1e-10f);
  }
  for (int off = 32; off; off >>= 1) local += __shfl_down(local, off, 64);
  if ((tid & 63) == 0) ws4[tid >> 6] = local;
  __syncthreads();
  if (tid == 0) {
    float H = ws4[0] + ws4[1] + ws4[2] + ws4[3];   // negative
    out[(size_t)NROWS * 512]     = 1.25f * sse[0] / 33554432.0f;
    out[(size_t)NROWS * 512 + 1] = expf(-H);
  }
}

extern "C" void kernel_launch(void* const* d_in, const int* in_sizes, int n_in,
                              void* d_out, int out_size, void* d_ws, size_t ws_size,
                              hipStream_t stream)
{
  const float* inputs = (const float*)d_in[0];
  const float* emb    = (const float*)d_in[1];
  const float* W_in   = (const float*)d_in[2];
  const float* b_in   = (const float*)d_in[3];
  const float* W_out  = (const float*)d_in[4];
  const float* b_out  = (const float*)d_in[5];
  float* out = (float*)d_out;

  char* ws = (char*)d_ws;
  float*    Dtab   = (float*)(ws + 0);                 // 8 MB
  __bf16*   X      = (__bf16*)(ws + 8388608);          // 8 MB
  __bf16*   Efrag  = (__bf16*)(ws + 16777216);         // 512 KB
  __bf16*   Wfrag  = (__bf16*)(ws + 17301504);         // 64 KB
  float*    chalf  = (float*)(ws + 17367040);          // 16 KB
  unsigned* idx    = (unsigned*)(ws + 17383424);       // 256 KB
  unsigned* counts = (unsigned*)(ws + 17645568);       // 16 KB
  float*    sse    = (float*)(ws + 17661952);

  k_prep  <<<1441, 256, 0, stream>>>(emb, W_in, W_out, b_out, Dtab, Efrag, Wfrag, chalf, counts, sse);
  k_xproj <<<512,  256, 0, stream>>>(inputs, (const bf16x8*)Wfrag, b_in, X);
  k_argmin<<<512,  256, 0, stream>>>(X, (const bf16x8*)Efrag, chalf, idx, counts);
  k_output<<<2048, 256, 0, stream>>>(inputs, Dtab, idx, out, sse);
  k_final <<<1,    256, 0, stream>>>(counts, sse, out);
}